// Round 5
// baseline (502.440 us; speedup 1.0000x reference)
//
#include <hip/hip_runtime.h>
#include <hip/hip_bf16.h>
#include <math.h>

#define EPSF 1e-5f
#define SCALEF 0.17677669529663687f   // 32^-0.5
#define LOG2E 1.4426950408889634f

typedef unsigned short u16;
typedef unsigned int u32;
typedef __attribute__((ext_vector_type(8))) short bf16x8;
typedef __attribute__((ext_vector_type(4))) float f32x4;

__device__ __forceinline__ float b2f(u16 u) {
    union { unsigned int i; float f; } v; v.i = ((unsigned int)u) << 16; return v.f;
}
__device__ __forceinline__ u16 f2b(float f) {
    union { float f; unsigned int i; } v; v.f = f;
    unsigned int x = v.i;
    return (u16)((x + 0x7fffu + ((x >> 16) & 1u)) >> 16);  // RNE, finite inputs
}
__device__ __forceinline__ u32 fbits(float f) {
    union { float f; u32 u; } v; v.f = f; return v.u;
}
__device__ __forceinline__ float dexp2(float x) {
#if __has_builtin(__builtin_amdgcn_exp2f)
    return __builtin_amdgcn_exp2f(x);
#else
    return exp2f(x);
#endif
}
__device__ __forceinline__ u32 pack_trunc(float p0, float p1) {
#if __has_builtin(__builtin_amdgcn_perm)
    return __builtin_amdgcn_perm(fbits(p1), fbits(p0), 0x07060302u);  // {p1.hi, p0.hi}
#else
    return (fbits(p0) >> 16) | (fbits(p1) & 0xffff0000u);
#endif
}

// ---------------- fp32 -> bf16 convert (vectorized x4) ----------------
__global__ void convert_f32_bf16(const float* __restrict__ src, u16* __restrict__ dst, int n4) {
    int i = blockIdx.x * 256 + threadIdx.x;
    if (i >= n4) return;
    float4 v = ((const float4*)src)[i];
    ushort4 o;
    o.x = f2b(v.x); o.y = f2b(v.y); o.z = f2b(v.z); o.w = f2b(v.w);
    ((ushort4*)dst)[i] = o;
}

// ---------------- subsample gather (bf16 x_b -> bf16 x_sub) ----------------
__global__ void gather_sub_bf16(const u16* __restrict__ xb, u16* __restrict__ xsub, int n8) {
    int i = blockIdx.x * 256 + threadIdx.x;
    if (i >= n8) return;
    int e = i << 3;
    int row = e >> 8;
    int col = e & 255;
    int b = row / 320;
    int t = row - b * 320;
    int n;
    if (t < 256) n = ((t >> 4) << 6) + ((t & 15) << 1);
    else { int tt = t - 256; n = 1024 + ((tt >> 3) << 5) + ((tt & 7) << 1); }
    *(int4*)(xsub + e) = *(const int4*)(xb + ((size_t)(b * 1280 + n)) * 256 + col);
}

// ---------------- column sums of X [rows][256] (bf16) -> out[256] (fp32 atomics) ----------------
__global__ void colsum256(const u16* __restrict__ X, int rowsPerBlock, float* __restrict__ out) {
    int c = threadIdx.x;
    int r0 = blockIdx.x * rowsPerBlock;
    float s = 0.f;
    for (int r = 0; r < rowsPerBlock; ++r) s += b2f(X[(size_t)(r0 + r) * 256 + c]);
    atomicAdd(&out[c], s);
}

// ---------------- Gram: Gpart[z] = X_z^T X_z over block's row range (bf16 MFMA, fp32 out) ----------------
__global__ __launch_bounds__(512) void gram256(const u16* __restrict__ X, int rowsPerBlock,
                                               float* __restrict__ Gpart) {
    __shared__ u16 Tt[256 * 72];   // transposed tile: Tt[ch][row], 64 rows, pad 72
    const int tid = threadIdx.x;
    const int rp = tid & 31, cg = tid >> 5;     // rowpair 0..31, colgroup 0..15
    const int wv = tid >> 6, lane = tid & 63;
    const int quad = lane >> 4, lc = lane & 15;
    const int wm = wv >> 1, wn = wv & 1;
    const int r0 = blockIdx.x * rowsPerBlock;

    f32x4 acc[4][8];
#pragma unroll
    for (int i = 0; i < 4; ++i)
#pragma unroll
        for (int j = 0; j < 8; ++j) acc[i][j] = (f32x4){0.f, 0.f, 0.f, 0.f};

    for (int rc = 0; rc < rowsPerBlock; rc += 64) {
        __syncthreads();
        union { int4 v; u16 u[8]; } ld[2][2];
        size_t base = (size_t)(r0 + rc + rp * 2) * 256 + cg * 16;
        ld[0][0].v = *(const int4*)(X + base);
        ld[0][1].v = *(const int4*)(X + base + 8);
        ld[1][0].v = *(const int4*)(X + base + 256);
        ld[1][1].v = *(const int4*)(X + base + 264);
        u32* T32 = (u32*)Tt;
#pragma unroll
        for (int j = 0; j < 16; ++j) {
            u32 pk = (u32)ld[0][j >> 3].u[j & 7] | ((u32)ld[1][j >> 3].u[j & 7] << 16);
            T32[(cg * 16 + j) * 36 + rp] = pk;
        }
        __syncthreads();
#pragma unroll
        for (int k0 = 0; k0 < 64; k0 += 32) {
            bf16x8 af[4], bfr[8];
#pragma unroll
            for (int mi = 0; mi < 4; ++mi) af[mi] = *(const bf16x8*)&Tt[(wm * 64 + mi * 16 + lc) * 72 + k0 + quad * 8];
#pragma unroll
            for (int ni = 0; ni < 8; ++ni) bfr[ni] = *(const bf16x8*)&Tt[(wn * 128 + ni * 16 + lc) * 72 + k0 + quad * 8];
#pragma unroll
            for (int mi = 0; mi < 4; ++mi)
#pragma unroll
                for (int ni = 0; ni < 8; ++ni)
                    acc[mi][ni] = __builtin_amdgcn_mfma_f32_16x16x32_bf16(af[mi], bfr[ni], acc[mi][ni], 0, 0, 0);
        }
    }
    float* out = Gpart + (size_t)blockIdx.x * 65536;
#pragma unroll
    for (int mi = 0; mi < 4; ++mi)
#pragma unroll
        for (int ni = 0; ni < 8; ++ni)
#pragma unroll
            for (int r = 0; r < 4; ++r)
                out[(wm * 64 + mi * 16 + quad * 4 + r) * 256 + wn * 128 + ni * 16 + lc] = acc[mi][ni][r];
}

__global__ void reduce_gpart(const float* __restrict__ Gp, float* __restrict__ G, int nz) {
    int i = blockIdx.x * 256 + threadIdx.x;   // float4 index, 16384 total
    float4 s = {0.f, 0.f, 0.f, 0.f};
    for (int z = 0; z < nz; ++z) {
        float4 v = ((const float4*)(Gp + (size_t)z * 65536))[i];
        s.x += v.x; s.y += v.y; s.z += v.z; s.w += v.w;
    }
    ((float4*)G)[i] = s;
}

// ---------------- BN affine from Gram: var_c = w_c^T G w_c /N - m^2, m = w_c.colsum/N ----------------
__global__ void stats_from_gram(const float* __restrict__ G, const float* __restrict__ colsum,
                                const u16* __restrict__ Wb, const float* __restrict__ g,
                                const float* __restrict__ beta, float inv_n, float scale,
                                int cols, float* __restrict__ AB) {
    const int c = blockIdx.x, t = threadIdx.x;
    __shared__ float wsh[256];
    __shared__ float red[4][2];
    wsh[t] = b2f(Wb[c * 256 + t]);
    __syncthreads();
    float wt = wsh[t];
    float acc = 0.f;
#pragma unroll 4
    for (int j = 0; j < 256; ++j) acc += G[j * 256 + t] * wsh[j];   // G symmetric: column t
    float vterm = wt * acc;
    float mterm = wt * colsum[t];
#pragma unroll
    for (int d = 1; d < 64; d <<= 1) {
        vterm += __shfl_xor(vterm, d);
        mterm += __shfl_xor(mterm, d);
    }
    if ((t & 63) == 0) { red[t >> 6][0] = vterm; red[t >> 6][1] = mterm; }
    __syncthreads();
    if (t == 0) {
        float V = red[0][0] + red[1][0] + red[2][0] + red[3][0];
        float M = red[0][1] + red[1][1] + red[2][1] + red[3][1];
        float m = M * inv_n;
        float var = V * inv_n - m * m;
        float a = g[c] * rsqrtf(var + EPSF) * scale;
        AB[c] = a;
        AB[cols + c] = beta[c] * scale - m * a;
    }
}

// ---------------- GEMM: C = A * W^T with fused BN-stats epilogue (for q and p) ----------------
template<int OUT_F32>
__global__ __launch_bounds__(256) void gemm_bt(const u16* __restrict__ A, const u16* __restrict__ Bw,
                                               void* __restrict__ Cv, int M, int N, int K,
                                               float* __restrict__ sums) {
    __shared__ u16 As[128 * 40];
    __shared__ u16 Bs[128 * 40];
    __shared__ float sumbuf[4][64][2];
    const int tid = threadIdx.x;
    const int wave = tid >> 6, lane = tid & 63;
    const int quad = lane >> 4, lc = lane & 15;
    const int wr = wave >> 1, wc = wave & 1;
    const int m0 = blockIdx.x * 128, n0 = blockIdx.y * 128;
    const int lrow = tid >> 2;
    const int lk = (tid & 3) << 3;

    f32x4 acc[4][4];
#pragma unroll
    for (int i = 0; i < 4; ++i)
#pragma unroll
        for (int j = 0; j < 4; ++j) acc[i][j] = (f32x4){0.f, 0.f, 0.f, 0.f};

    for (int k0 = 0; k0 < K; k0 += 32) {
        __syncthreads();
        *(int4*)&As[lrow * 40 + lk]        = *(const int4*)(A  + (size_t)(m0 + lrow) * K + k0 + lk);
        *(int4*)&As[(lrow + 64) * 40 + lk] = *(const int4*)(A  + (size_t)(m0 + lrow + 64) * K + k0 + lk);
        *(int4*)&Bs[lrow * 40 + lk]        = *(const int4*)(Bw + (size_t)(n0 + lrow) * K + k0 + lk);
        *(int4*)&Bs[(lrow + 64) * 40 + lk] = *(const int4*)(Bw + (size_t)(n0 + lrow + 64) * K + k0 + lk);
        __syncthreads();
        bf16x8 af[4], bfr[4];
#pragma unroll
        for (int mi = 0; mi < 4; ++mi) af[mi]  = *(const bf16x8*)&As[(wr * 64 + mi * 16 + lc) * 40 + quad * 8];
#pragma unroll
        for (int ni = 0; ni < 4; ++ni) bfr[ni] = *(const bf16x8*)&Bs[(wc * 64 + ni * 16 + lc) * 40 + quad * 8];
#pragma unroll
        for (int mi = 0; mi < 4; ++mi)
#pragma unroll
            for (int ni = 0; ni < 4; ++ni)
                acc[mi][ni] = __builtin_amdgcn_mfma_f32_16x16x32_bf16(af[mi], bfr[ni], acc[mi][ni], 0, 0, 0);
    }
    float ps[4], ps2[4];
#pragma unroll
    for (int ni = 0; ni < 4; ++ni) { ps[ni] = 0.f; ps2[ni] = 0.f; }
#pragma unroll
    for (int mi = 0; mi < 4; ++mi)
#pragma unroll
        for (int ni = 0; ni < 4; ++ni)
#pragma unroll
            for (int r = 0; r < 4; ++r) {
                int row = m0 + wr * 64 + mi * 16 + quad * 4 + r;
                int cn  = n0 + wc * 64 + ni * 16 + lc;
                float v = acc[mi][ni][r];
                ps[ni] += v; ps2[ni] += v * v;
                if (OUT_F32) ((float*)Cv)[(size_t)row * N + cn] = v;
                else         ((u16*)Cv)[(size_t)row * N + cn] = f2b(v);
            }
#pragma unroll
    for (int ni = 0; ni < 4; ++ni) {
        ps[ni]  += __shfl_xor(ps[ni], 16);  ps[ni]  += __shfl_xor(ps[ni], 32);
        ps2[ni] += __shfl_xor(ps2[ni], 16); ps2[ni] += __shfl_xor(ps2[ni], 32);
    }
    if (quad == 0) {
#pragma unroll
        for (int ni = 0; ni < 4; ++ni) {
            sumbuf[wave][ni * 16 + lc][0] = ps[ni];
            sumbuf[wave][ni * 16 + lc][1] = ps2[ni];
        }
    }
    __syncthreads();
    {
        int which = tid & 1, idx = (tid >> 1) & 63, wcg = tid >> 7;
        int channel = n0 + wcg * 64 + idx;
        float v = sumbuf[wcg][idx][which] + sumbuf[wcg + 2][idx][which];
        int rep = blockIdx.x & 7;
        atomicAdd(&sums[(rep * 2 + which) * N + channel], v);
    }
}

// ---------------- fold BN into per-channel affine (sums replicated x8) ----------------
__global__ void finalize_bn(const float* __restrict__ sum2, const float* __restrict__ g,
                            const float* __restrict__ beta, int cols, float inv_n, float scale,
                            float* __restrict__ AB) {
    int c = blockIdx.x * 256 + threadIdx.x;
    if (c >= cols) return;
    float s = 0.f, s2 = 0.f;
#pragma unroll
    for (int r = 0; r < 8; ++r) {
        s  += sum2[(r * 2 + 0) * cols + c];
        s2 += sum2[(r * 2 + 1) * cols + c];
    }
    float m = s * inv_n;
    float var = s2 * inv_n - m * m;
    float a = g[c] * rsqrtf(var + EPSF) * scale;
    AB[c] = a;
    AB[cols + c] = beta[c] * scale - m * a;
}

// ---------------- GEMM_KV fused: y = x @ Wkv^T, BN affine inline, writes K [b][h][1280][32]
// (interleaved rows) + V^T [bh][d][tok] (per-wave LDS transpose). ----------------
__global__ __launch_bounds__(256) void gemm_kv_fused(const u16* __restrict__ A, const u16* __restrict__ Bw,
                                                     const float* __restrict__ AB,
                                                     u16* __restrict__ Kn, u16* __restrict__ Vtn) {
    __shared__ u16 As[128 * 40];
    __shared__ u16 Bs[128 * 40];
    __shared__ u16 Tws[4 * 1152];   // per-wave 16ch x 72 transpose buffer
    const int tid = threadIdx.x;
    const int wave = tid >> 6, lane = tid & 63;
    const int quad = lane >> 4, lc = lane & 15;
    const int wr = wave >> 1, wc = wave & 1;
    const int m0 = blockIdx.x * 128, n0 = blockIdx.y * 128;
    const int lrow = tid >> 2;
    const int lk = (tid & 3) << 3;
    const int K = 256;

    f32x4 acc[4][4];
#pragma unroll
    for (int i = 0; i < 4; ++i)
#pragma unroll
        for (int j = 0; j < 4; ++j) acc[i][j] = (f32x4){0.f, 0.f, 0.f, 0.f};

    for (int k0 = 0; k0 < K; k0 += 32) {
        __syncthreads();
        *(int4*)&As[lrow * 40 + lk]        = *(const int4*)(A  + (size_t)(m0 + lrow) * K + k0 + lk);
        *(int4*)&As[(lrow + 64) * 40 + lk] = *(const int4*)(A  + (size_t)(m0 + lrow + 64) * K + k0 + lk);
        *(int4*)&Bs[lrow * 40 + lk]        = *(const int4*)(Bw + (size_t)(n0 + lrow) * K + k0 + lk);
        *(int4*)&Bs[(lrow + 64) * 40 + lk] = *(const int4*)(Bw + (size_t)(n0 + lrow + 64) * K + k0 + lk);
        __syncthreads();
        bf16x8 af[4], bfr[4];
#pragma unroll
        for (int mi = 0; mi < 4; ++mi) af[mi]  = *(const bf16x8*)&As[(wr * 64 + mi * 16 + lc) * 40 + quad * 8];
#pragma unroll
        for (int ni = 0; ni < 4; ++ni) bfr[ni] = *(const bf16x8*)&Bs[(wc * 64 + ni * 16 + lc) * 40 + quad * 8];
#pragma unroll
        for (int mi = 0; mi < 4; ++mi)
#pragma unroll
            for (int ni = 0; ni < 4; ++ni)
                acc[mi][ni] = __builtin_amdgcn_mfma_f32_16x16x32_bf16(af[mi], bfr[ni], acc[mi][ni], 0, 0, 0);
    }
    // epilogue: affine + split K/V writes
    const int bb_ = m0 / 1280;
    const int tokbase = m0 - bb_ * 1280;
    u16* Tw = &Tws[wave * 1152];
#pragma unroll
    for (int ni = 0; ni < 4; ++ni) {
        int cg0 = n0 + wc * 64 + ni * 16;
        int h = cg0 / 96;
        int rem = cg0 - h * 96;
        int c = cg0 + lc;
        float aa = AB[c], bb2 = AB[768 + c];
        if (rem < 32) {
            // K group: [b][h][row'][32], rows interleaved (even keys in first 16 of each 32-group)
#pragma unroll
            for (int mi = 0; mi < 4; ++mi)
#pragma unroll
                for (int r = 0; r < 4; ++r) {
                    int n = tokbase + wr * 64 + mi * 16 + quad * 4 + r;
                    int rowp = (n & ~31) | ((n & 1) << 4) | ((n & 31) >> 1);
                    Kn[(((size_t)(bb_ * 8 + h)) * 1280 + rowp) * 32 + rem + lc] = f2b(acc[mi][ni][r] * aa + bb2);
                }
        } else {
            // V group: transpose 16ch x 64tok via wave-private LDS, coalesced Vt writes
#pragma unroll
            for (int mi = 0; mi < 4; ++mi)
#pragma unroll
                for (int r = 0; r < 4; ++r)
                    Tw[lc * 72 + mi * 16 + quad * 4 + r] = f2b(acc[mi][ni][r] * aa + bb2);
            int dvl = lane >> 2, tg = lane & 3;
            int dv = rem - 32 + dvl;
            size_t vbase = ((size_t)(bb_ * 8 + h) * 64 + dv) * 1280 + tokbase + wr * 64;
            bf16x8 v0 = *(const bf16x8*)&Tw[dvl * 72 + tg * 8];
            bf16x8 v1 = *(const bf16x8*)&Tw[dvl * 72 + 32 + tg * 8];
            *(bf16x8*)(Vtn + vbase + tg * 8) = v0;
            *(bf16x8*)(Vtn + vbase + 32 + tg * 8) = v1;
        }
    }
}

// ---------------- fused attention v4 ----------------
// grid (8 heads, 64 batch), block 256 = 4 waves; each wave: 16 q-rows x 5 tiles.
// log2-domain scores (exp2), trunc-pack P, lsum via ones-MFMA, double-buffered P
// with PV(t-1) issued BEFORE S(t) so LDS reads never wait on current exp chain.
__global__ __launch_bounds__(256, 2) void attn_kernel4(const u16* __restrict__ Kn, const u16* __restrict__ Vtn,
                                                       const u16* __restrict__ q_raw, const float* __restrict__ ABq,
                                                       u16* __restrict__ o_act) {
    __shared__ u16 Ps[25600];   // [wave][buf][j][16 x 40]
    const int tid = threadIdx.x;
    const int wave = tid >> 6, lane = tid & 63;
    const int quad = lane >> 4, lc = lane & 15;
    const int h = blockIdx.x, b = blockIdx.y;
    const int bh = b * 8 + h;

    float qa[8], qb[8];
#pragma unroll
    for (int j = 0; j < 8; ++j) { int c = h * 32 + quad * 8 + j; qa[j] = ABq[c]; qb[j] = ABq[256 + c]; }
    bf16x8 qf[5];
#pragma unroll
    for (int j = 0; j < 5; ++j) {
        const u16* qs = q_raw + ((size_t)(b * 320 + j * 64 + wave * 16 + lc)) * 256 + h * 32 + quad * 8;
        union { int4 v; u16 u[8]; } ld; ld.v = *(const int4*)qs;
        union { bf16x8 v; u16 u[8]; } st;
#pragma unroll
        for (int jj = 0; jj < 8; ++jj) st.u[jj] = f2b(b2f(ld.u[jj]) * qa[jj] + qb[jj]);
        qf[j] = st.v;
    }

    const u16* Kp = Kn + (size_t)bh * 1280 * 32 + lc * 32 + quad * 8;
    const u16* Vp = Vtn + ((size_t)bh * 64 + lc) * 1280 + quad * 8;
    u16* Pw = &Ps[wave * 6400];

    f32x4 acc[5][4];
    f32x4 accl[5];
#pragma unroll
    for (int j = 0; j < 5; ++j) {
        accl[j] = (f32x4){0.f, 0.f, 0.f, 0.f};
#pragma unroll
        for (int i = 0; i < 4; ++i) acc[j][i] = (f32x4){0.f, 0.f, 0.f, 0.f};
    }
    bf16x8 ones;
    { union { bf16x8 v; u16 u[8]; } o_;
#pragma unroll
      for (int i = 0; i < 8; ++i) o_.u[i] = 0x3F80;  // bf16 1.0
      ones = o_.v; }
    bf16x8 vprev[4];

    for (int kc = 0; kc < 1280; kc += 32) {
        const int buf = (kc >> 5) & 1;
        bf16x8 kf0 = *(const bf16x8*)(Kp + kc * 32);          // even keys kc+2lc
        bf16x8 kf1 = *(const bf16x8*)(Kp + kc * 32 + 512);    // odd keys  kc+2lc+1
        bf16x8 vf0 = *(const bf16x8*)(Vp + kc);
        bf16x8 vf1 = *(const bf16x8*)(Vp + 16 * 1280 + kc);
        bf16x8 vf2 = *(const bf16x8*)(Vp + 32 * 1280 + kc);
        bf16x8 vf3 = *(const bf16x8*)(Vp + 48 * 1280 + kc);
        if (kc) {   // PV for previous chunk first (P in other buffer, V in vprev)
            const u16* Pr = Pw + (buf ^ 1) * 3200;
#pragma unroll
            for (int j = 0; j < 5; ++j) {
                bf16x8 pf = *(const bf16x8*)&Pr[j * 640 + lc * 40 + quad * 8];
                acc[j][0] = __builtin_amdgcn_mfma_f32_16x16x32_bf16(pf, vprev[0], acc[j][0], 0, 0, 0);
                acc[j][1] = __builtin_amdgcn_mfma_f32_16x16x32_bf16(pf, vprev[1], acc[j][1], 0, 0, 0);
                acc[j][2] = __builtin_amdgcn_mfma_f32_16x16x32_bf16(pf, vprev[2], acc[j][2], 0, 0, 0);
                acc[j][3] = __builtin_amdgcn_mfma_f32_16x16x32_bf16(pf, vprev[3], acc[j][3], 0, 0, 0);
                accl[j]   = __builtin_amdgcn_mfma_f32_16x16x32_bf16(pf, ones,     accl[j],   0, 0, 0);
            }
        }
        u16* Pb = Pw + buf * 3200;
#pragma unroll
        for (int j = 0; j < 5; ++j) {
            f32x4 z = (f32x4){0.f, 0.f, 0.f, 0.f};
            f32x4 s0 = __builtin_amdgcn_mfma_f32_16x16x32_bf16(qf[j], kf0, z, 0, 0, 0);
            f32x4 s1 = __builtin_amdgcn_mfma_f32_16x16x32_bf16(qf[j], kf1, z, 0, 0, 0);
#pragma unroll
            for (int r = 0; r < 4; ++r) {
                float p0 = dexp2(s0[r]);
                float p1 = dexp2(s1[r]);
                *(u32*)&Pb[j * 640 + (quad * 4 + r) * 40 + 2 * lc] = pack_trunc(p0, p1);
            }
        }
        vprev[0] = vf0; vprev[1] = vf1; vprev[2] = vf2; vprev[3] = vf3;
    }
    {   // tail PV (last chunk wrote buf=1)
        const u16* Pr = Pw + 3200;
#pragma unroll
        for (int j = 0; j < 5; ++j) {
            bf16x8 pf = *(const bf16x8*)&Pr[j * 640 + lc * 40 + quad * 8];
            acc[j][0] = __builtin_amdgcn_mfma_f32_16x16x32_bf16(pf, vprev[0], acc[j][0], 0, 0, 0);
            acc[j][1] = __builtin_amdgcn_mfma_f32_16x16x32_bf16(pf, vprev[1], acc[j][1], 0, 0, 0);
            acc[j][2] = __builtin_amdgcn_mfma_f32_16x16x32_bf16(pf, vprev[2], acc[j][2], 0, 0, 0);
            acc[j][3] = __builtin_amdgcn_mfma_f32_16x16x32_bf16(pf, vprev[3], acc[j][3], 0, 0, 0);
            accl[j]   = __builtin_amdgcn_mfma_f32_16x16x32_bf16(pf, ones,     accl[j],   0, 0, 0);
        }
    }
    // epilogue: accl[j][r] = full row sum (replicated over lc); hard_swish; store
#pragma unroll
    for (int j = 0; j < 5; ++j) {
        float inv[4];
#pragma unroll
        for (int r = 0; r < 4; ++r) inv[r] = 1.f / accl[j][r];
        int qrow = b * 320 + j * 64 + wave * 16 + quad * 4;
#pragma unroll
        for (int nt = 0; nt < 4; ++nt)
#pragma unroll
            for (int r = 0; r < 4; ++r) {
                float o = acc[j][nt][r] * inv[r];
                float hs = o * fminf(fmaxf(o + 3.f, 0.f), 6.f) * (1.f / 6.f);
                o_act[(size_t)(qrow + r) * 512 + h * 64 + nt * 16 + lc] = f2b(hs);
            }
    }
}

// ---------------- final BN apply -> d_out (fp32) ----------------
__global__ void bn_apply_out(const float* __restrict__ praw, const float* __restrict__ ABp,
                             float* __restrict__ out, int n4) {
    int i = blockIdx.x * 256 + threadIdx.x;
    if (i >= n4) return;
    int e = i << 2;
    int c = e & 511;
    float4 v = ((const float4*)praw)[i];
    float4 o;
    o.x = v.x * ABp[c]     + ABp[512 + c];
    o.y = v.y * ABp[c + 1] + ABp[512 + c + 1];
    o.z = v.z * ABp[c + 2] + ABp[512 + c + 2];
    o.w = v.w * ABp[c + 3] + ABp[512 + c + 3];
    ((float4*)out)[i] = o;
}

// ---------------- launcher ----------------
extern "C" void kernel_launch(void* const* d_in, const int* in_sizes, int n_in,
                              void* d_out, int out_size, void* d_ws, size_t ws_size,
                              hipStream_t stream) {
    const float* x   = (const float*)d_in[0];
    const float* Wkv = (const float*)d_in[1];
    const float* gkv = (const float*)d_in[2];
    const float* bkv = (const float*)d_in[3];
    const float* Wq  = (const float*)d_in[4];
    const float* gq  = (const float*)d_in[5];
    const float* bq  = (const float*)d_in[6];
    const float* Wp  = (const float*)d_in[7];
    const float* gp  = (const float*)d_in[8];
    const float* bp  = (const float*)d_in[9];
    float* out = (float*)d_out;

    char* ws = (char*)d_ws;
    size_t off = 0;
    auto alloc = [&](size_t bytes) -> void* {
        void* p = ws + off;
        off += (bytes + 255) & ~(size_t)255;
        return p;
    };
    u16*   q_raw  = (u16*)alloc(20480ull * 256 * 2);          // 10.5 MB
    // slot1: x_b (last read: gemm_kv_fused) -> p_raw (written by gemm_p, later)
    void*  slot1  = alloc(81920ull * 256 * 2);                // 41.9 MB
    u16*   x_b    = (u16*)slot1;
    float* p_raw  = (float*)slot1;
    // slot2: xsub (last read: gemm_q) -> o_act (written by attn, later)
    void*  slot2  = alloc(20480ull * 512 * 2);                // 21.0 MB
    u16*   xsub_b = (u16*)slot2;
    u16*   o_act  = (u16*)slot2;
    u16*   K_nat  = (u16*)alloc(64ull * 8 * 1280 * 32 * 2);   // 41.9 MB  [b][h][1280][32]
    u16*   Vt     = (u16*)alloc(512ull * 64 * 1280 * 2);      // 83.9 MB
    u16*   Wkv_b  = (u16*)alloc(768ull * 256 * 2);
    u16*   Wq_b   = (u16*)alloc(256ull * 256 * 2);
    u16*   Wp_b   = (u16*)alloc(512ull * 512 * 2);
    float* Gpart  = (float*)alloc(64ull * 65536 * 4);         // 16.8 MB
    float* G      = (float*)alloc(65536 * 4);
    float* statz  = (float*)alloc((256 + 4096 + 8192) * 4);   // colsum | sums_q | sums_p
    float* colsum_x = statz;
    float* sums_q   = statz + 256;
    float* sums_p   = statz + 256 + 4096;
    float* ABkv = (float*)alloc(1536 * 4);
    float* ABq  = (float*)alloc(512 * 4);
    float* ABp  = (float*)alloc(1024 * 4);

    dim3 blk(256);
    hipMemsetAsync(statz, 0, (256 + 4096 + 8192) * 4, stream);

    convert_f32_bf16<<<20480, blk, 0, stream>>>(x,   x_b,   5242880);
    convert_f32_bf16<<<192,   blk, 0, stream>>>(Wkv, Wkv_b, 49152);
    convert_f32_bf16<<<64,    blk, 0, stream>>>(Wq,  Wq_b,  16384);
    convert_f32_bf16<<<256,   blk, 0, stream>>>(Wp,  Wp_b,  65536);
    gather_sub_bf16<<<2560,   blk, 0, stream>>>(x_b, xsub_b, 655360);

    // KV BN stats, closed-form from Gram of x (before the GEMM)
    colsum256<<<256, blk, 0, stream>>>(x_b, 320, colsum_x);
    gram256<<<64, dim3(512), 0, stream>>>(x_b, 1280, Gpart);
    reduce_gpart<<<64, blk, 0, stream>>>(Gpart, G, 64);
    stats_from_gram<<<768, blk, 0, stream>>>(G, colsum_x, Wkv_b, gkv, bkv,
                                             1.f / 81920.f, 1.f, 768, ABkv);

    // Q projection (fused stats epilogue), affine applied in attn with SCALE*log2e folded
    gemm_bt<0><<<dim3(160, 2), blk, 0, stream>>>(xsub_b, Wq_b, q_raw, 20480, 256, 256, sums_q);
    finalize_bn<<<1, blk, 0, stream>>>(sums_q, gq, bq, 256, 1.f / 20480.f, SCALEF * LOG2E, ABq);

    // KV projection writes normalized K (compact interleaved, per-head) + V^T directly
    gemm_kv_fused<<<dim3(640, 6), blk, 0, stream>>>(x_b, Wkv_b, ABkv, K_nat, Vt);

    attn_kernel4<<<dim3(8, 64), blk, 0, stream>>>(K_nat, Vt, q_raw, ABq, o_act);

    gemm_bt<1><<<dim3(160, 4), blk, 0, stream>>>(o_act, Wp_b, p_raw, 20480, 512, 512, sums_p);
    finalize_bn<<<2, blk, 0, stream>>>(sums_p, gp, bp, 512, 1.f / 20480.f, 1.f, ABp);

    bn_apply_out<<<10240, blk, 0, stream>>>(p_raw, ABp, out, 2621440);
}